// Round 13
// baseline (582.684 us; speedup 1.0000x reference)
//
#include <hip/hip_runtime.h>
#include <hip/hip_bf16.h>
#include <stdint.h>

#define DEVFN static __device__ __forceinline__

typedef __attribute__((ext_vector_type(8))) short bf16x8;
typedef __attribute__((ext_vector_type(4))) float f32x4;
typedef unsigned short u16;
typedef unsigned int u32;
typedef unsigned long long u64;

DEVFN u16 f2bf(float f) {
    union { float f; u32 u; } v; v.f = f;
    u32 r = v.u + 0x7FFFu + ((v.u >> 16) & 1u);
    return (u16)(r >> 16);
}

DEVFN void g2l16(const void* g, void* l) {
    __builtin_amdgcn_global_load_lds(
        (const __attribute__((address_space(1))) u32*)g,
        (__attribute__((address_space(3))) u32*)l, 16, 0, 0);
}

DEVFN void hbar() {
    __asm__ __volatile__("" ::: "memory");
    __builtin_amdgcn_s_barrier();
    __asm__ __volatile__("" ::: "memory");
}
DEVFN void vm4() { asm volatile("s_waitcnt vmcnt(4)" ::: "memory"); }
DEVFN void vm0() { asm volatile("s_waitcnt vmcnt(0)" ::: "memory"); }

#define MFMA16(a, b, c) __builtin_amdgcn_mfma_f32_16x16x32_bf16(a, b, c, 0, 0, 0)

// ===== fused top: swiglu (blocks < nwsw) + expert gate_up (rest) ============
// swiglu path: single-barrier 8-phase (R11, 206us). e-gu: two-barrier (R6).
__global__ __launch_bounds__(512, 2) void gemm8_top_k(
    const u16* __restrict__ xb,
    const u16* __restrict__ Bgs, const u16* __restrict__ Bus,
    u16* __restrict__ hs,
    const u16* __restrict__ Beg, const u16* __restrict__ Beu,
    const int* __restrict__ tok, const int* __restrict__ cntp,
    u16* __restrict__ eact,
    int K, int nwsw, int nxsw, int ldsw, int Ie, int cap)
{
    extern __shared__ char smraw[];
    char* smA = smraw;
    char* smB = smraw + 65536;

    const int tid = threadIdx.x;
    const int lane = tid & 63, wv = tid >> 6;
    const int wm = wv >> 2, wn = wv & 3;
    const int l15 = lane & 15, kg = lane >> 4;
    const int lq = lane >> 4;

    auto frag = [&](const char* base, int r, int c) -> bf16x8 {
        return *(const __attribute__((address_space(3))) bf16x8*)
            (base + r * 128 + (((c) ^ (r & 7)) << 4));
    };

    if ((int)blockIdx.x < nwsw) {
        // ---------------- shared SwiGLU path ----------------
        const int id = (blockIdx.x & 7) * (nwsw >> 3) + (blockIdx.x >> 3);
        const int m0 = (id / nxsw) * 256, n0 = (id % nxsw) * 128;

        const u16* Ap  = xb  + (long)m0 * K;
        const u16* Bgp = Bgs + (long)n0 * K;
        const u16* Bup = Bus + (long)n0 * K;

        f32x4 accg[8][2], accu[8][2];
#pragma unroll
        for (int i = 0; i < 8; ++i)
#pragma unroll
            for (int j = 0; j < 2; ++j) {
                accg[i][j] = f32x4{0.f, 0.f, 0.f, 0.f};
                accu[i][j] = f32x4{0.f, 0.f, 0.f, 0.f};
            }

        auto stA = [&](int kt, int hh, int buf) {
            const u16* src = Ap + ((long)hh * 128) * K + kt * 64;
            char* dst = smA + buf * 32768 + hh * 16384;
#pragma unroll
            for (int i = 0; i < 2; ++i) {
                int slot = i * 512 + tid;
                int row = slot >> 3, ch = slot & 7;
                g2l16(src + (long)row * K + ((ch ^ (row & 7)) << 3),
                      dst + slot * 16);
            }
        };
        auto stB = [&](int kt, int hh, int buf) {
            const u16* src = (hh ? Bup : Bgp) + kt * 64;
            char* dst = smB + buf * 32768 + hh * 16384;
#pragma unroll
            for (int i = 0; i < 2; ++i) {
                int slot = i * 512 + tid;
                int row = slot >> 3, ch = slot & 7;
                g2l16(src + (long)row * K + ((ch ^ (row & 7)) << 3),
                      dst + slot * 16);
            }
        };

        stA(0, 0, 0); stA(0, 1, 0);
        stB(0, 0, 0); stB(0, 1, 0);
        stB(1, 0, 1); stB(1, 1, 1);
        vm4();
        hbar();

        const int nk = K >> 6;
        for (int kt = 0; kt < nk; kt += 2) {
            const bool more = (kt + 2) < nk;
#pragma unroll
            for (int h = 0; h < 2; ++h) {
                const char* ab = smA + h * 32768;
                const char* bb = smB + h * 32768;
                bf16x8 bgv[2][2], buv[2][2];
#pragma unroll
                for (int p = 0; p < 4; ++p) {
                    if (p == 0) {
#pragma unroll
                        for (int fn = 0; fn < 2; ++fn)
#pragma unroll
                            for (int s = 0; s < 2; ++s) {
                                int rB = wn * 32 + fn * 16 + l15;
                                bgv[fn][s] = frag(bb, rB, s * 4 + kg);
                                buv[fn][s] = frag(bb + 16384, rB, s * 4 + kg);
                            }
                    }
                    bf16x8 av[2][2];
#pragma unroll
                    for (int am = 0; am < 2; ++am)
#pragma unroll
                        for (int s = 0; s < 2; ++s)
                            av[am][s] = frag(ab,
                                wm * 128 + (p * 2 + am) * 16 + l15, s * 4 + kg);
                    if (h == 0) {
                        if (p == 1)      { stA(kt + 1, 0, 1); stA(kt + 1, 1, 1); }
                        else if (p == 2) { if (more) stB(kt + 2, 0, 0); }
                        else if (p == 3) {
                            if (more) { stB(kt + 2, 1, 0); vm4(); } else vm0();
                        }
                    } else {
                        if (more) {
                            if (p == 1)      stA(kt + 2, 0, 0);
                            else if (p == 2) { stA(kt + 2, 1, 0);
                                               stB(kt + 3, 0, 1); }
                            else if (p == 3) { stB(kt + 3, 1, 1); vm4(); }
                        }
                    }
                    hbar();
                    __builtin_amdgcn_sched_barrier(0);
                    __builtin_amdgcn_s_setprio(1);
#pragma unroll
                    for (int am = 0; am < 2; ++am)
#pragma unroll
                        for (int s = 0; s < 2; ++s)
#pragma unroll
                            for (int fn = 0; fn < 2; ++fn) {
                                accg[p * 2 + am][fn] = MFMA16(av[am][s],
                                    bgv[fn][s], accg[p * 2 + am][fn]);
                                accu[p * 2 + am][fn] = MFMA16(av[am][s],
                                    buv[fn][s], accu[p * 2 + am][fn]);
                            }
                    __builtin_amdgcn_s_setprio(0);
                }
            }
        }

#pragma unroll
        for (int fm = 0; fm < 8; ++fm)
#pragma unroll
            for (int j = 0; j < 4; ++j) {
                int row = m0 + wm * 128 + fm * 16 + lq * 4 + j;
#pragma unroll
                for (int fn = 0; fn < 2; ++fn) {
                    int col = n0 + wn * 32 + fn * 16 + l15;
                    float g = accg[fm][fn][j], u = accu[fm][fn][j];
                    float s = g * (1.f / (1.f + __expf(-g))) * u;
                    hs[(long)row * ldsw + col] = f2bf(s);
                }
            }
    } else {
        // ---------------- expert gate_up path ----------------
        const int bx = blockIdx.x - nwsw;
        const int e = bx / 48;
        const int rem = bx % 48;
        const int m0 = (rem / 6) * 256;
        if (m0 >= cntp[e]) return;
        const int n0 = (rem % 6) * 128;

        const int r0 = tid >> 3, ch = tid & 7;
        const int swz = (ch ^ (r0 & 7)) << 3;
        const int* tseg = tok + (long)e * cap + m0;
        const u16* pa00 = xb + (long)tseg[r0] * K + swz;
        const u16* pa01 = xb + (long)tseg[64 + r0] * K + swz;
        const u16* pa10 = xb + (long)tseg[128 + r0] * K + swz;
        const u16* pa11 = xb + (long)tseg[192 + r0] * K + swz;

        const u16* Bgp = Beg + ((long)e * Ie + n0) * K;
        const u16* Bup = Beu + ((long)e * Ie + n0) * K;

        f32x4 accg[8][2], accu[8][2];
#pragma unroll
        for (int i = 0; i < 8; ++i)
#pragma unroll
            for (int j = 0; j < 2; ++j) {
                accg[i][j] = f32x4{0.f, 0.f, 0.f, 0.f};
                accu[i][j] = f32x4{0.f, 0.f, 0.f, 0.f};
            }

        auto stA = [&](int kt, int hh, int buf) {
            char* dst = smA + buf * 32768 + hh * 16384;
            const u16* p0 = hh ? pa10 : pa00;
            const u16* p1 = hh ? pa11 : pa01;
            g2l16(p0 + kt * 64, dst + (long)tid * 16);
            g2l16(p1 + kt * 64, dst + (long)(512 + tid) * 16);
        };
        auto stB = [&](int kt, int hh, int buf) {
            const u16* src = (hh ? Bup : Bgp) + kt * 64;
            char* dst = smB + buf * 32768 + hh * 16384;
#pragma unroll
            for (int i = 0; i < 2; ++i) {
                int slot = i * 512 + tid;
                int row = slot >> 3, c = slot & 7;
                g2l16(src + (long)row * K + ((c ^ (row & 7)) << 3),
                      dst + slot * 16);
            }
        };

        stA(0, 0, 0); stA(0, 1, 0);
        stB(0, 0, 0); stB(0, 1, 0);
        stB(1, 0, 1); stB(1, 1, 1);
        vm4();
        hbar();

        const int nk = K >> 6;
        for (int kt = 0; kt < nk; kt += 2) {
            const bool more = (kt + 2) < nk;
#pragma unroll
            for (int h = 0; h < 2; ++h) {
                const char* ab = smA + h * 32768;
                const char* bb = smB + h * 32768;
                bf16x8 bgv[2][2], buv[2][2];
#pragma unroll
                for (int p = 0; p < 4; ++p) {
                    if (p == 0) {
#pragma unroll
                        for (int fn = 0; fn < 2; ++fn)
#pragma unroll
                            for (int s = 0; s < 2; ++s) {
                                int rB = wn * 32 + fn * 16 + l15;
                                bgv[fn][s] = frag(bb, rB, s * 4 + kg);
                                buv[fn][s] = frag(bb + 16384, rB, s * 4 + kg);
                            }
                    }
                    bf16x8 av[2][2];
#pragma unroll
                    for (int am = 0; am < 2; ++am)
#pragma unroll
                        for (int s = 0; s < 2; ++s)
                            av[am][s] = frag(ab,
                                wm * 128 + (p * 2 + am) * 16 + l15, s * 4 + kg);
                    if (h == 0) {
                        if (p == 0)      { stA(kt + 1, 0, 1); stA(kt + 1, 1, 1); }
                        else if (p == 1) { if (more) stB(kt + 2, 0, 0); }
                        else if (p == 2) { if (more) stB(kt + 2, 1, 0); }
                        else             { if (more) vm4(); else vm0(); }
                    } else {
                        if (more) {
                            if (p == 0)      stA(kt + 2, 0, 0);
                            else if (p == 1) stA(kt + 2, 1, 0);
                            else if (p == 2) stB(kt + 3, 0, 1);
                            else             { stB(kt + 3, 1, 1); vm4(); }
                        }
                    }
                    hbar();
                    __builtin_amdgcn_sched_barrier(0);
                    __builtin_amdgcn_s_setprio(1);
#pragma unroll
                    for (int am = 0; am < 2; ++am)
#pragma unroll
                        for (int s = 0; s < 2; ++s)
#pragma unroll
                            for (int fn = 0; fn < 2; ++fn) {
                                accg[p * 2 + am][fn] = MFMA16(av[am][s],
                                    bgv[fn][s], accg[p * 2 + am][fn]);
                                accu[p * 2 + am][fn] = MFMA16(av[am][s],
                                    buv[fn][s], accu[p * 2 + am][fn]);
                            }
                    __builtin_amdgcn_s_setprio(0);
                    __builtin_amdgcn_sched_barrier(0);
                    hbar();
                }
            }
        }

#pragma unroll
        for (int fm = 0; fm < 8; ++fm)
#pragma unroll
            for (int j = 0; j < 4; ++j) {
                long row = (long)e * cap + m0 + wm * 128 + fm * 16 + lq * 4 + j;
#pragma unroll
                for (int fn = 0; fn < 2; ++fn) {
                    int col = n0 + wn * 32 + fn * 16 + l15;
                    float g = accg[fm][fn][j], u = accu[fm][fn][j];
                    float s = g * (1.f / (1.f + __expf(-g))) * u;
                    eact[row * Ie + col] = f2bf(s);
                }
            }
    }
}

// ================= 2-phase helpers ==========================================
template<int NSLOT>
DEVFN void stage(const u16* __restrict__ src, int ldk, u16* lds, int tid) {
#pragma unroll
    for (int i = 0; i < NSLOT / 256; ++i) {
        int slot = i * 256 + tid;
        int row = slot >> 2, chunk = slot & 3;
        int kg = chunk ^ ((row >> 1) & 3);
        g2l16(src + (long)row * ldk + kg * 8, lds + slot * 8);
    }
}

DEVFN bf16x8 ld_frag(const u16* lds, int row, int kg) {
    int chunk = kg ^ ((row >> 1) & 3);
    const u16* p = lds + row * 32 + chunk * 8;
    return *(const __attribute__((address_space(3))) bf16x8*)p;
}

// ===== fused down: shared down (blocks < nwsd) + expert down (rest) ========
// Both paths atomicAdd into pre-zeroed out (launch-internal order undefined).
__global__ __launch_bounds__(256) void gemm_down_fused_k(
    const u16* __restrict__ hs, const u16* __restrict__ Bds,
    const float* __restrict__ sig,
    const u16* __restrict__ eact, const u16* __restrict__ Bed,
    const int* __restrict__ tok, const float* __restrict__ wrow,
    const int* __restrict__ cntp,
    float* __restrict__ out,
    int Ksh, int Ke, int ldc, int cap, int nwsd)
{
    __shared__ u16 sm[2][8192];
    const int tid = threadIdx.x;
    const int lane = tid & 63, wv = tid >> 6;
    const int wm = wv >> 1, wn = wv & 1;
    const int l15 = lane & 15, kg = lane >> 4, lq = lane >> 4;

    const u16 *Ab, *Bb;
    int K;
    int m0, n0;
    int e = 0;
    bool shared_path = ((int)blockIdx.x < nwsd);
    if (shared_path) {
        m0 = (blockIdx.x / 16) * 128;
        n0 = (blockIdx.x % 16) * 128;
        K = Ksh;
        Ab = hs + (long)m0 * K;
        Bb = Bds + (long)n0 * K;
    } else {
        int bx = blockIdx.x - nwsd;
        e = bx >> 8;
        int rem = bx & 255;
        m0 = (rem >> 4) * 128;
        if (m0 >= cntp[e]) return;
        n0 = (rem & 15) * 128;
        K = Ke;
        Ab = eact + ((long)e * cap + m0) * K;
        Bb = Bed + ((long)e * ldc + n0) * K;
    }

    f32x4 acc[4][4];
#pragma unroll
    for (int i = 0; i < 4; ++i)
#pragma unroll
        for (int j = 0; j < 4; ++j) acc[i][j] = f32x4{0.f, 0.f, 0.f, 0.f};

    stage<512>(Ab, K, &sm[0][0], tid);
    stage<512>(Bb, K, &sm[0][4096], tid);

    const int nk = K >> 5;
    for (int kt = 0; kt < nk; ++kt) {
        const int cur = kt & 1;
        __syncthreads();
        if (kt + 1 < nk) {
            stage<512>(Ab + (kt + 1) * 32, K, &sm[cur ^ 1][0], tid);
            stage<512>(Bb + (kt + 1) * 32, K, &sm[cur ^ 1][4096], tid);
        }
        bf16x8 av[4], bv[4];
#pragma unroll
        for (int f = 0; f < 4; ++f) {
            av[f] = ld_frag(&sm[cur][0],    wm * 64 + f * 16 + l15, kg);
            bv[f] = ld_frag(&sm[cur][4096], wn * 64 + f * 16 + l15, kg);
        }
#pragma unroll
        for (int fm = 0; fm < 4; ++fm)
#pragma unroll
            for (int fn = 0; fn < 4; ++fn)
                acc[fm][fn] = MFMA16(av[fm], bv[fn], acc[fm][fn]);
    }

    if (shared_path) {
#pragma unroll
        for (int fm = 0; fm < 4; ++fm)
#pragma unroll
            for (int j = 0; j < 4; ++j) {
                int row = m0 + wm * 64 + fm * 16 + lq * 4 + j;
                float gmul = sig[row];
#pragma unroll
                for (int fn = 0; fn < 4; ++fn) {
                    int col = n0 + wn * 64 + fn * 16 + l15;
                    atomicAdd(out + (long)row * ldc + col,
                              acc[fm][fn][j] * gmul);
                }
            }
    } else {
#pragma unroll
        for (int fm = 0; fm < 4; ++fm)
#pragma unroll
            for (int j = 0; j < 4; ++j) {
                long crow = (long)e * cap + m0 + wm * 64 + fm * 16 + lq * 4 + j;
                float w = wrow[crow];
                if (w != 0.f) {
                    long t = tok[crow];
#pragma unroll
                    for (int fn = 0; fn < 4; ++fn) {
                        int col = n0 + wn * 64 + fn * 16 + l15;
                        atomicAdd(out + t * ldc + col, acc[fm][fn][j] * w);
                    }
                }
            }
    }
}

// ====================== small kernels ======================================
__global__ __launch_bounds__(256) void router_k(
    const float* __restrict__ x, const float* __restrict__ rw,
    const float* __restrict__ sgw, float* __restrict__ logits,
    int2* __restrict__ te, float2* __restrict__ tw,
    float* __restrict__ sig, int T, int H)
{
    const int tid = threadIdx.x, lane = tid & 63, wv = tid >> 6;
    const int t = blockIdx.x * 4 + wv;
    const float* xr = x + (long)t * H;
    float acc[8] = {0, 0, 0, 0, 0, 0, 0, 0};
    float as = 0.f;
    for (int h = lane; h < H; h += 64) {
        float xv = xr[h];
        const float* r = rw + h * 8;
#pragma unroll
        for (int e = 0; e < 8; ++e) acc[e] += xv * r[e];
        as += xv * sgw[h];
    }
#pragma unroll
    for (int off = 32; off; off >>= 1) {
#pragma unroll
        for (int e = 0; e < 8; ++e) acc[e] += __shfl_xor(acc[e], off);
        as += __shfl_xor(as, off);
    }
    if (lane == 0) {
        float mx = acc[0];
#pragma unroll
        for (int e = 1; e < 8; ++e) mx = fmaxf(mx, acc[e]);
        float p[8], sum = 0.f;
#pragma unroll
        for (int e = 0; e < 8; ++e) { p[e] = expf(acc[e] - mx); sum += p[e]; }
        int i1 = 0;
#pragma unroll
        for (int e = 1; e < 8; ++e) if (p[e] > p[i1]) i1 = e;
        int i2 = (i1 == 0) ? 1 : 0;
#pragma unroll
        for (int e = 0; e < 8; ++e) if (e != i1 && p[e] > p[i2]) i2 = e;
        float den = p[i1] + p[i2];
        te[t] = make_int2(i1, i2);
        tw[t] = make_float2(p[i1] / den, p[i2] / den);
#pragma unroll
        for (int e = 0; e < 8; ++e) logits[(long)t * 8 + e] = acc[e];
        sig[t] = 1.f / (1.f + expf(-as));
    }
}

__global__ __launch_bounds__(256) void compact_k(
    const int2* __restrict__ te, const float2* __restrict__ tw,
    int* __restrict__ tok, float* __restrict__ wrow,
    int* __restrict__ cntp, int T, int cap)
{
    const int e = blockIdx.x;
    const int tid = threadIdx.x, lane = tid & 63, wv = tid >> 6;
    __shared__ int wtot[4];
    int cnt = 0;
    for (int c0 = 0; c0 < T; c0 += 256) {
        int t = c0 + tid;
        int2 ids = te[t];
        float2 ws = tw[t];
        float w = (ids.x == e) ? ws.x : ((ids.y == e) ? ws.y : -1.f);
        bool sel = (w >= 0.f);
        u64 b = __ballot(sel);
        int rln = __popcll(b & ((1ull << lane) - 1ull));
        if (lane == 0) wtot[wv] = __popcll(b);
        __syncthreads();
        int rank = rln, tot = 0;
#pragma unroll
        for (int k = 0; k < 4; ++k) { if (k < wv) rank += wtot[k]; tot += wtot[k]; }
        if (sel) {
            int pos = cnt + rank;
            if (pos < cap) {
                tok[(long)e * cap + pos] = t;
                wrow[(long)e * cap + pos] = w;
            }
        }
        cnt += tot;
        __syncthreads();
    }
    if (cnt > cap) cnt = cap;
    int cp = (cnt + 255) & ~255;
    if (cp > cap) cp = cap;
    for (int p = cnt + tid; p < cp; p += 256) {
        tok[(long)e * cap + p] = 0;
        wrow[(long)e * cap + p] = 0.f;
    }
    if (tid == 0) cntp[e] = cp;
}

__global__ __launch_bounds__(256) void transpose_k(
    const float* __restrict__ src0, long src_zstr, int src_ld,
    u16* __restrict__ dst0, long dst_zstr, int dst_ld)
{
    __shared__ float tile[64][65];
    const float* src = src0 + (long)blockIdx.z * src_zstr;
    u16* dst = dst0 + (long)blockIdx.z * dst_zstr;
    int r0 = blockIdx.y * 64, c0 = blockIdx.x * 64;
    int tx = threadIdx.x & 63, ty = threadIdx.x >> 6;  // 64 x 4
#pragma unroll
    for (int k = 0; k < 16; ++k)
        tile[ty + 4 * k][tx] = src[(long)(r0 + ty + 4 * k) * src_ld + c0 + tx];
    __syncthreads();
#pragma unroll
    for (int k = 0; k < 16; ++k)
        dst[(long)(c0 + ty + 4 * k) * dst_ld + r0 + tx] = f2bf(tile[tx][ty + 4 * k]);
}

__global__ __launch_bounds__(256) void cvt_x_k(const float* __restrict__ x,
                                               u16* __restrict__ xb)
{
    long i = ((long)blockIdx.x * 256 + threadIdx.x) * 4;
    float4 v = *(const float4*)(x + i);
    union { u16 s[4]; uint2 v2; } o;
    o.s[0] = f2bf(v.x); o.s[1] = f2bf(v.y); o.s[2] = f2bf(v.z); o.s[3] = f2bf(v.w);
    *(uint2*)(xb + i) = o.v2;
}

extern "C" void kernel_launch(void* const* d_in, const int* in_sizes, int n_in,
                              void* d_out, int out_size, void* d_ws, size_t ws_size,
                              hipStream_t stream) {
    (void)in_sizes; (void)n_in; (void)out_size; (void)ws_size;
    const int Hd = 2048, E = 8, I = 768, SH = 5632, T = 4096, CAP = 2048;

    const float* x    = (const float*)d_in[0];
    const float* rw   = (const float*)d_in[1];
    const float* egu  = (const float*)d_in[2];
    const float* edw  = (const float*)d_in[3];
    const float* sgw  = (const float*)d_in[4];
    const float* suw  = (const float*)d_in[5];
    const float* sdw  = (const float*)d_in[6];
    const float* segw = (const float*)d_in[7];
    float* out = (float*)d_out;
    float* logits = out + (size_t)T * Hd;

    char* wsp = (char*)d_ws;
    size_t off = 0;
    auto alloc = [&](size_t bytes) {
        void* p = wsp + off; off += (bytes + 255) & ~(size_t)255; return p;
    };
    u16* xb   = (u16*)alloc((size_t)T * Hd * 2);
    u16* Bgs  = (u16*)alloc((size_t)SH * Hd * 2);
    u16* Bus  = (u16*)alloc((size_t)SH * Hd * 2);
    u16* Bds  = (u16*)alloc((size_t)Hd * SH * 2);
    u16* Beg  = (u16*)alloc((size_t)E * I * Hd * 2);
    u16* Beu  = (u16*)alloc((size_t)E * I * Hd * 2);
    u16* Bed  = (u16*)alloc((size_t)E * Hd * I * 2);
    u16* hs   = (u16*)alloc((size_t)T * SH * 2);
    u16* eact = (u16*)alloc((size_t)E * CAP * I * 2);
    int2*   te   = (int2*)alloc((size_t)T * 8);
    float2* tw   = (float2*)alloc((size_t)T * 8);
    int*    tok  = (int*)alloc((size_t)E * CAP * 4);
    float*  wrow = (float*)alloc((size_t)E * CAP * 4);
    int*    cntp = (int*)alloc(64);
    float*  sig  = (float*)alloc((size_t)T * 4);

    hipFuncSetAttribute((const void*)gemm8_top_k,
                        hipFuncAttributeMaxDynamicSharedMemorySize, 131072);

    hipMemsetAsync(out, 0, (size_t)T * Hd * 4, stream);
    cvt_x_k<<<(T * Hd) / 1024, 256, 0, stream>>>(x, xb);
    router_k<<<T / 4, 256, 0, stream>>>(x, rw, segw, logits, te, tw, sig, T, Hd);
    compact_k<<<E, 256, 0, stream>>>(te, tw, tok, wrow, cntp, T, CAP);

    transpose_k<<<dim3(SH / 64, Hd / 64), 256, 0, stream>>>(sgw, 0, SH, Bgs, 0, Hd);
    transpose_k<<<dim3(SH / 64, Hd / 64), 256, 0, stream>>>(suw, 0, SH, Bus, 0, Hd);
    transpose_k<<<dim3(Hd / 64, SH / 64), 256, 0, stream>>>(sdw, 0, Hd, Bds, 0, SH);
    transpose_k<<<dim3(I / 64, Hd / 64, E), 256, 0, stream>>>(
        egu, (long)Hd * 2 * I, 2 * I, Beg, (long)I * Hd, Hd);
    transpose_k<<<dim3(I / 64, Hd / 64, E), 256, 0, stream>>>(
        egu + I, (long)Hd * 2 * I, 2 * I, Beu, (long)I * Hd, Hd);
    transpose_k<<<dim3(Hd / 64, I / 64, E), 256, 0, stream>>>(
        edw, (long)I * Hd, Hd, Bed, (long)Hd * I, I);

    // fused top: swiglu (704 blocks) + expert gate_up (384 blocks, tail-fill)
    const int NWSW = (SH / 128) * (T / 256);          // 704, %8 == 0
    gemm8_top_k<<<dim3(NWSW + 6 * (CAP / 256) * E), 512, 131072, stream>>>(
        xb, Bgs, Bus, hs, Beg, Beu, tok, cntp, eact,
        Hd, NWSW, SH / 128, SH, I, CAP);
    // fused down: shared down (512 blocks) + expert down (2048, early-exit)
    const int NWSD = (T / 128) * (Hd / 128);          // 512
    gemm_down_fused_k<<<dim3(NWSD + 256 * E), 256, 0, stream>>>(
        hs, Bds, sig, eact, Bed, tok, wrow, cntp, out,
        SH, I, Hd, CAP, NWSD);
}

// Round 14
// 575.326 us; speedup vs baseline: 1.0128x; 1.0128x over previous
//
#include <hip/hip_runtime.h>
#include <hip/hip_bf16.h>
#include <stdint.h>

#define DEVFN static __device__ __forceinline__

typedef __attribute__((ext_vector_type(8))) short bf16x8;
typedef __attribute__((ext_vector_type(4))) float f32x4;
typedef unsigned short u16;
typedef unsigned int u32;
typedef unsigned long long u64;

DEVFN u16 f2bf(float f) {
    union { float f; u32 u; } v; v.f = f;
    u32 r = v.u + 0x7FFFu + ((v.u >> 16) & 1u);
    return (u16)(r >> 16);
}

DEVFN void g2l16(const void* g, void* l) {
    __builtin_amdgcn_global_load_lds(
        (const __attribute__((address_space(1))) u32*)g,
        (__attribute__((address_space(3))) u32*)l, 16, 0, 0);
}

DEVFN void hbar() {
    __asm__ __volatile__("" ::: "memory");
    __builtin_amdgcn_s_barrier();
    __asm__ __volatile__("" ::: "memory");
}
DEVFN void vm4() { asm volatile("s_waitcnt vmcnt(4)" ::: "memory"); }
DEVFN void vm0() { asm volatile("s_waitcnt vmcnt(0)" ::: "memory"); }

#define MFMA16(a, b, c) __builtin_amdgcn_mfma_f32_16x16x32_bf16(a, b, c, 0, 0, 0)

// ============ 8-phase 256-tile swiglu GEMM (round-6 proven) =================
__global__ __launch_bounds__(512, 2) void gemm8_swiglu_k(
    const u16* __restrict__ A, const u16* __restrict__ Bg,
    const u16* __restrict__ Bu, u16* __restrict__ out,
    int K, int nx, int ldc)
{
    extern __shared__ char smraw[];
    char* smA = smraw;
    char* smB = smraw + 65536;

    const int tid = threadIdx.x;
    const int lane = tid & 63, wv = tid >> 6;
    const int wm = wv >> 2, wn = wv & 3;
    const int l15 = lane & 15, kg = lane >> 4;

    const int nwg = gridDim.x;
    const int id = (blockIdx.x & 7) * (nwg >> 3) + (blockIdx.x >> 3);
    const int m0 = (id / nx) * 256, n0 = (id % nx) * 128;

    const u16* Ap  = A  + (long)m0 * K;
    const u16* Bgp = Bg + (long)n0 * K;
    const u16* Bup = Bu + (long)n0 * K;

    f32x4 accg[8][2], accu[8][2];
#pragma unroll
    for (int i = 0; i < 8; ++i)
#pragma unroll
        for (int j = 0; j < 2; ++j) {
            accg[i][j] = f32x4{0.f, 0.f, 0.f, 0.f};
            accu[i][j] = f32x4{0.f, 0.f, 0.f, 0.f};
        }

    auto stA = [&](int kt, int hh, int buf) {
        const u16* src = Ap + ((long)hh * 128) * K + kt * 64;
        char* dst = smA + buf * 32768 + hh * 16384;
#pragma unroll
        for (int i = 0; i < 2; ++i) {
            int slot = i * 512 + tid;
            int row = slot >> 3, ch = slot & 7;
            g2l16(src + (long)row * K + ((ch ^ (row & 7)) << 3), dst + slot * 16);
        }
    };
    auto stB = [&](int kt, int hh, int buf) {
        const u16* src = (hh ? Bup : Bgp) + kt * 64;
        char* dst = smB + buf * 32768 + hh * 16384;
#pragma unroll
        for (int i = 0; i < 2; ++i) {
            int slot = i * 512 + tid;
            int row = slot >> 3, ch = slot & 7;
            g2l16(src + (long)row * K + ((ch ^ (row & 7)) << 3), dst + slot * 16);
        }
    };
    auto frag = [&](const char* base, int r, int c) -> bf16x8 {
        return *(const __attribute__((address_space(3))) bf16x8*)
            (base + r * 128 + (((c) ^ (r & 7)) << 4));
    };

    stA(0, 0, 0); stA(0, 1, 0);
    stB(0, 0, 0); stB(0, 1, 0);
    stB(1, 0, 1); stB(1, 1, 1);
    vm4();
    hbar();

    const int nk = K >> 6;
    for (int kt = 0; kt < nk; kt += 2) {
        const bool more = (kt + 2) < nk;
#pragma unroll
        for (int h = 0; h < 2; ++h) {
            const char* ab = smA + h * 32768;
            const char* bb = smB + h * 32768;
            bf16x8 bgv[2][2], buv[2][2];
#pragma unroll
            for (int p = 0; p < 4; ++p) {
                if (p == 0) {
#pragma unroll
                    for (int fn = 0; fn < 2; ++fn)
#pragma unroll
                        for (int s = 0; s < 2; ++s) {
                            int rB = wn * 32 + fn * 16 + l15;
                            bgv[fn][s] = frag(bb, rB, s * 4 + kg);
                            buv[fn][s] = frag(bb + 16384, rB, s * 4 + kg);
                        }
                }
                bf16x8 av[2][2];
#pragma unroll
                for (int am = 0; am < 2; ++am)
#pragma unroll
                    for (int s = 0; s < 2; ++s)
                        av[am][s] = frag(ab, wm * 128 + (p * 2 + am) * 16 + l15,
                                         s * 4 + kg);
                if (h == 0) {
                    if (p == 0)      { stA(kt + 1, 0, 1); stA(kt + 1, 1, 1); }
                    else if (p == 1) { if (more) stB(kt + 2, 0, 0); }
                    else if (p == 2) { if (more) stB(kt + 2, 1, 0); }
                    else             { if (more) vm4(); else vm0(); }
                } else {
                    if (more) {
                        if (p == 0)      stA(kt + 2, 0, 0);
                        else if (p == 1) stA(kt + 2, 1, 0);
                        else if (p == 2) stB(kt + 3, 0, 1);
                        else             { stB(kt + 3, 1, 1); vm4(); }
                    }
                }
                hbar();
                __builtin_amdgcn_sched_barrier(0);
                __builtin_amdgcn_s_setprio(1);
#pragma unroll
                for (int am = 0; am < 2; ++am)
#pragma unroll
                    for (int s = 0; s < 2; ++s)
#pragma unroll
                        for (int fn = 0; fn < 2; ++fn) {
                            accg[p * 2 + am][fn] = MFMA16(av[am][s], bgv[fn][s],
                                                          accg[p * 2 + am][fn]);
                            accu[p * 2 + am][fn] = MFMA16(av[am][s], buv[fn][s],
                                                          accu[p * 2 + am][fn]);
                        }
                __builtin_amdgcn_s_setprio(0);
                __builtin_amdgcn_sched_barrier(0);
                hbar();
            }
        }
    }

    const int lq = lane >> 4;
#pragma unroll
    for (int fm = 0; fm < 8; ++fm)
#pragma unroll
        for (int j = 0; j < 4; ++j) {
            int row = m0 + wm * 128 + fm * 16 + lq * 4 + j;
#pragma unroll
            for (int fn = 0; fn < 2; ++fn) {
                int col = n0 + wn * 32 + fn * 16 + l15;
                float g = accg[fm][fn][j], u = accu[fm][fn][j];
                float s = g * (1.f / (1.f + __expf(-g))) * u;
                out[(long)row * ldc + col] = f2bf(s);
            }
        }
}

// ===== expert gate_up: round-6 proven, token-gathered A rows ================
__global__ __launch_bounds__(512, 2) void gemm8e_swiglu_k(
    const u16* __restrict__ xb, const u16* __restrict__ Beg,
    const u16* __restrict__ Beu, const int* __restrict__ tok,
    const int* __restrict__ cntp, u16* __restrict__ eact,
    int K, int ldc, int cap)
{
    const int e = blockIdx.z;
    const int m0 = blockIdx.y * 256;
    if (m0 >= cntp[e]) return;
    const int n0 = blockIdx.x * 128;

    extern __shared__ char smraw[];
    char* smA = smraw;
    char* smB = smraw + 65536;

    const int tid = threadIdx.x;
    const int lane = tid & 63, wv = tid >> 6;
    const int wm = wv >> 2, wn = wv & 3;
    const int l15 = lane & 15, kg = lane >> 4;

    const int r0 = tid >> 3, ch = tid & 7;
    const int swz = (ch ^ (r0 & 7)) << 3;
    const int* tseg = tok + (long)e * cap + m0;
    const u16* pa00 = xb + (long)tseg[r0] * K + swz;
    const u16* pa01 = xb + (long)tseg[64 + r0] * K + swz;
    const u16* pa10 = xb + (long)tseg[128 + r0] * K + swz;
    const u16* pa11 = xb + (long)tseg[192 + r0] * K + swz;

    const u16* Bgp = Beg + ((long)e * ldc + n0) * K;
    const u16* Bup = Beu + ((long)e * ldc + n0) * K;

    f32x4 accg[8][2], accu[8][2];
#pragma unroll
    for (int i = 0; i < 8; ++i)
#pragma unroll
        for (int j = 0; j < 2; ++j) {
            accg[i][j] = f32x4{0.f, 0.f, 0.f, 0.f};
            accu[i][j] = f32x4{0.f, 0.f, 0.f, 0.f};
        }

    auto stA = [&](int kt, int hh, int buf) {
        char* dst = smA + buf * 32768 + hh * 16384;
        const u16* p0 = hh ? pa10 : pa00;
        const u16* p1 = hh ? pa11 : pa01;
        g2l16(p0 + kt * 64, dst + (long)tid * 16);
        g2l16(p1 + kt * 64, dst + (long)(512 + tid) * 16);
    };
    auto stB = [&](int kt, int hh, int buf) {
        const u16* src = (hh ? Bup : Bgp) + kt * 64;
        char* dst = smB + buf * 32768 + hh * 16384;
#pragma unroll
        for (int i = 0; i < 2; ++i) {
            int slot = i * 512 + tid;
            int row = slot >> 3, c = slot & 7;
            g2l16(src + (long)row * K + ((c ^ (row & 7)) << 3), dst + slot * 16);
        }
    };
    auto frag = [&](const char* base, int r, int c) -> bf16x8 {
        return *(const __attribute__((address_space(3))) bf16x8*)
            (base + r * 128 + (((c) ^ (r & 7)) << 4));
    };

    stA(0, 0, 0); stA(0, 1, 0);
    stB(0, 0, 0); stB(0, 1, 0);
    stB(1, 0, 1); stB(1, 1, 1);
    vm4();
    hbar();

    const int nk = K >> 6;
    for (int kt = 0; kt < nk; kt += 2) {
        const bool more = (kt + 2) < nk;
#pragma unroll
        for (int h = 0; h < 2; ++h) {
            const char* ab = smA + h * 32768;
            const char* bb = smB + h * 32768;
            bf16x8 bgv[2][2], buv[2][2];
#pragma unroll
            for (int p = 0; p < 4; ++p) {
                if (p == 0) {
#pragma unroll
                    for (int fn = 0; fn < 2; ++fn)
#pragma unroll
                        for (int s = 0; s < 2; ++s) {
                            int rB = wn * 32 + fn * 16 + l15;
                            bgv[fn][s] = frag(bb, rB, s * 4 + kg);
                            buv[fn][s] = frag(bb + 16384, rB, s * 4 + kg);
                        }
                }
                bf16x8 av[2][2];
#pragma unroll
                for (int am = 0; am < 2; ++am)
#pragma unroll
                    for (int s = 0; s < 2; ++s)
                        av[am][s] = frag(ab, wm * 128 + (p * 2 + am) * 16 + l15,
                                         s * 4 + kg);
                if (h == 0) {
                    if (p == 0)      { stA(kt + 1, 0, 1); stA(kt + 1, 1, 1); }
                    else if (p == 1) { if (more) stB(kt + 2, 0, 0); }
                    else if (p == 2) { if (more) stB(kt + 2, 1, 0); }
                    else             { if (more) vm4(); else vm0(); }
                } else {
                    if (more) {
                        if (p == 0)      stA(kt + 2, 0, 0);
                        else if (p == 1) stA(kt + 2, 1, 0);
                        else if (p == 2) stB(kt + 3, 0, 1);
                        else             { stB(kt + 3, 1, 1); vm4(); }
                    }
                }
                hbar();
                __builtin_amdgcn_sched_barrier(0);
                __builtin_amdgcn_s_setprio(1);
#pragma unroll
                for (int am = 0; am < 2; ++am)
#pragma unroll
                    for (int s = 0; s < 2; ++s)
#pragma unroll
                        for (int fn = 0; fn < 2; ++fn) {
                            accg[p * 2 + am][fn] = MFMA16(av[am][s], bgv[fn][s],
                                                          accg[p * 2 + am][fn]);
                            accu[p * 2 + am][fn] = MFMA16(av[am][s], buv[fn][s],
                                                          accu[p * 2 + am][fn]);
                        }
                __builtin_amdgcn_s_setprio(0);
                __builtin_amdgcn_sched_barrier(0);
                hbar();
            }
        }
    }

    const int lq = lane >> 4;
#pragma unroll
    for (int fm = 0; fm < 8; ++fm)
#pragma unroll
        for (int j = 0; j < 4; ++j) {
            long row = (long)e * cap + m0 + wm * 128 + fm * 16 + lq * 4 + j;
#pragma unroll
            for (int fn = 0; fn < 2; ++fn) {
                int col = n0 + wn * 32 + fn * 16 + l15;
                float g = accg[fm][fn][j], u = accu[fm][fn][j];
                float s = g * (1.f / (1.f + __expf(-g))) * u;
                eact[row * ldc + col] = f2bf(s);
            }
        }
}

// ================= 2-phase helpers/kernels ==================================
template<int NSLOT>
DEVFN void stage(const u16* __restrict__ src, int ldk, u16* lds, int tid) {
#pragma unroll
    for (int i = 0; i < NSLOT / 256; ++i) {
        int slot = i * 256 + tid;
        int row = slot >> 2, chunk = slot & 3;
        int kg = chunk ^ ((row >> 1) & 3);
        g2l16(src + (long)row * ldk + kg * 8, lds + slot * 8);
    }
}

DEVFN bf16x8 ld_frag(const u16* lds, int row, int kg) {
    int chunk = kg ^ ((row >> 1) & 3);
    const u16* p = lds + row * 32 + chunk * 8;
    return *(const __attribute__((address_space(3))) bf16x8*)p;
}

// shared down GEMM: out[M,N] = gvec[m] * A[M,K]*B[N,K]^T (proven 2-phase)
__global__ __launch_bounds__(256) void gemm_down_k(
    const u16* __restrict__ A, const u16* __restrict__ B,
    float* __restrict__ C, const float* __restrict__ gvec,
    int K, int ldc)
{
    __shared__ u16 sm[2][8192];
    const int tid = threadIdx.x;
    const int lane = tid & 63, wv = tid >> 6;
    const int wm = wv >> 1, wn = wv & 1;
    const int m0 = blockIdx.y * 128, n0 = blockIdx.x * 128;
    const u16* Ab = A + (long)m0 * K;
    const u16* Bb = B + (long)n0 * K;

    f32x4 acc[4][4];
#pragma unroll
    for (int i = 0; i < 4; ++i)
#pragma unroll
        for (int j = 0; j < 4; ++j) acc[i][j] = f32x4{0.f, 0.f, 0.f, 0.f};

    stage<512>(Ab, K, &sm[0][0], tid);
    stage<512>(Bb, K, &sm[0][4096], tid);

    const int nk = K >> 5;
    for (int kt = 0; kt < nk; ++kt) {
        const int cur = kt & 1;
        __syncthreads();
        if (kt + 1 < nk) {
            stage<512>(Ab + (kt + 1) * 32, K, &sm[cur ^ 1][0], tid);
            stage<512>(Bb + (kt + 1) * 32, K, &sm[cur ^ 1][4096], tid);
        }
        const int l15 = lane & 15, kg = lane >> 4;
        bf16x8 av[4], bv[4];
#pragma unroll
        for (int f = 0; f < 4; ++f) {
            av[f] = ld_frag(&sm[cur][0],    wm * 64 + f * 16 + l15, kg);
            bv[f] = ld_frag(&sm[cur][4096], wn * 64 + f * 16 + l15, kg);
        }
#pragma unroll
        for (int fm = 0; fm < 4; ++fm)
#pragma unroll
            for (int fn = 0; fn < 4; ++fn)
                acc[fm][fn] = MFMA16(av[fm], bv[fn], acc[fm][fn]);
    }

    const int l15 = lane & 15, lq = lane >> 4;
#pragma unroll
    for (int fm = 0; fm < 4; ++fm) {
#pragma unroll
        for (int j = 0; j < 4; ++j) {
            int row = m0 + wm * 64 + fm * 16 + lq * 4 + j;
            float gmul = gvec[row];
#pragma unroll
            for (int fn = 0; fn < 4; ++fn) {
                int col = n0 + wn * 64 + fn * 16 + l15;
                C[(long)row * ldc + col] = acc[fm][fn][j] * gmul;
            }
        }
    }
}

// expert down GEMM (grouped, 2-phase) + weighted scatter-add into out
__global__ __launch_bounds__(256) void gemm_down_moe_k(
    const u16* __restrict__ eact, const u16* __restrict__ Bed,
    float* __restrict__ out, const int* __restrict__ tok,
    const float* __restrict__ wrow, const int* __restrict__ cntp,
    int K, int ldc, int cap)
{
    const int e = blockIdx.z;
    const int m0 = blockIdx.y * 128;
    if (m0 >= cntp[e]) return;
    const int n0 = blockIdx.x * 128;

    __shared__ u16 sm[2][8192];
    const int tid = threadIdx.x;
    const int lane = tid & 63, wv = tid >> 6;
    const int wm = wv >> 1, wn = wv & 1;
    const u16* Ab = eact + ((long)e * cap + m0) * K;
    const u16* Bb = Bed + (long)e * ldc * K + (long)n0 * K;

    f32x4 acc[4][4];
#pragma unroll
    for (int i = 0; i < 4; ++i)
#pragma unroll
        for (int j = 0; j < 4; ++j) acc[i][j] = f32x4{0.f, 0.f, 0.f, 0.f};

    stage<512>(Ab, K, &sm[0][0], tid);
    stage<512>(Bb, K, &sm[0][4096], tid);

    const int nk = K >> 5;
    for (int kt = 0; kt < nk; ++kt) {
        const int cur = kt & 1;
        __syncthreads();
        if (kt + 1 < nk) {
            stage<512>(Ab + (kt + 1) * 32, K, &sm[cur ^ 1][0], tid);
            stage<512>(Bb + (kt + 1) * 32, K, &sm[cur ^ 1][4096], tid);
        }
        const int l15 = lane & 15, kg = lane >> 4;
        bf16x8 av[4], bv[4];
#pragma unroll
        for (int f = 0; f < 4; ++f) {
            av[f] = ld_frag(&sm[cur][0],    wm * 64 + f * 16 + l15, kg);
            bv[f] = ld_frag(&sm[cur][4096], wn * 64 + f * 16 + l15, kg);
        }
#pragma unroll
        for (int fm = 0; fm < 4; ++fm)
#pragma unroll
            for (int fn = 0; fn < 4; ++fn)
                acc[fm][fn] = MFMA16(av[fm], bv[fn], acc[fm][fn]);
    }

    const int l15 = lane & 15, lq = lane >> 4;
#pragma unroll
    for (int fm = 0; fm < 4; ++fm) {
#pragma unroll
        for (int j = 0; j < 4; ++j) {
            long crow = (long)e * cap + m0 + wm * 64 + fm * 16 + lq * 4 + j;
            float w = wrow[crow];
            if (w != 0.f) {
                long t = tok[crow];
#pragma unroll
                for (int fn = 0; fn < 4; ++fn) {
                    int col = n0 + wn * 64 + fn * 16 + l15;
                    atomicAdd(out + t * ldc + col, acc[fm][fn][j] * w);
                }
            }
        }
    }
}

// ====================== small kernels ======================================
__global__ __launch_bounds__(256) void router_k(
    const float* __restrict__ x, const float* __restrict__ rw,
    const float* __restrict__ sgw, float* __restrict__ logits,
    int2* __restrict__ te, float2* __restrict__ tw,
    float* __restrict__ sig, int T, int H)
{
    const int tid = threadIdx.x, lane = tid & 63, wv = tid >> 6;
    const int t = blockIdx.x * 4 + wv;
    const float* xr = x + (long)t * H;
    float acc[8] = {0, 0, 0, 0, 0, 0, 0, 0};
    float as = 0.f;
    for (int h = lane; h < H; h += 64) {
        float xv = xr[h];
        const float* r = rw + h * 8;
#pragma unroll
        for (int e = 0; e < 8; ++e) acc[e] += xv * r[e];
        as += xv * sgw[h];
    }
#pragma unroll
    for (int off = 32; off; off >>= 1) {
#pragma unroll
        for (int e = 0; e < 8; ++e) acc[e] += __shfl_xor(acc[e], off);
        as += __shfl_xor(as, off);
    }
    if (lane == 0) {
        float mx = acc[0];
#pragma unroll
        for (int e = 1; e < 8; ++e) mx = fmaxf(mx, acc[e]);
        float p[8], sum = 0.f;
#pragma unroll
        for (int e = 0; e < 8; ++e) { p[e] = expf(acc[e] - mx); sum += p[e]; }
        int i1 = 0;
#pragma unroll
        for (int e = 1; e < 8; ++e) if (p[e] > p[i1]) i1 = e;
        int i2 = (i1 == 0) ? 1 : 0;
#pragma unroll
        for (int e = 0; e < 8; ++e) if (e != i1 && p[e] > p[i2]) i2 = e;
        float den = p[i1] + p[i2];
        te[t] = make_int2(i1, i2);
        tw[t] = make_float2(p[i1] / den, p[i2] / den);
#pragma unroll
        for (int e = 0; e < 8; ++e) logits[(long)t * 8 + e] = acc[e];
        sig[t] = 1.f / (1.f + expf(-as));
    }
}

__global__ __launch_bounds__(256) void compact_k(
    const int2* __restrict__ te, const float2* __restrict__ tw,
    int* __restrict__ tok, float* __restrict__ wrow,
    int* __restrict__ cntp, int T, int cap)
{
    const int e = blockIdx.x;
    const int tid = threadIdx.x, lane = tid & 63, wv = tid >> 6;
    __shared__ int wtot[4];
    int cnt = 0;
    for (int c0 = 0; c0 < T; c0 += 256) {
        int t = c0 + tid;
        int2 ids = te[t];
        float2 ws = tw[t];
        float w = (ids.x == e) ? ws.x : ((ids.y == e) ? ws.y : -1.f);
        bool sel = (w >= 0.f);
        u64 b = __ballot(sel);
        int rln = __popcll(b & ((1ull << lane) - 1ull));
        if (lane == 0) wtot[wv] = __popcll(b);
        __syncthreads();
        int rank = rln, tot = 0;
#pragma unroll
        for (int k = 0; k < 4; ++k) { if (k < wv) rank += wtot[k]; tot += wtot[k]; }
        if (sel) {
            int pos = cnt + rank;
            if (pos < cap) {
                tok[(long)e * cap + pos] = t;
                wrow[(long)e * cap + pos] = w;
            }
        }
        cnt += tot;
        __syncthreads();
    }
    if (cnt > cap) cnt = cap;
    int cp = (cnt + 255) & ~255;
    if (cp > cap) cp = cap;
    for (int p = cnt + tid; p < cp; p += 256) {
        tok[(long)e * cap + p] = 0;
        wrow[(long)e * cap + p] = 0.f;
    }
    if (tid == 0) cntp[e] = cp;
}

__global__ __launch_bounds__(256) void transpose_k(
    const float* __restrict__ src0, long src_zstr, int src_ld,
    u16* __restrict__ dst0, long dst_zstr, int dst_ld)
{
    __shared__ float tile[64][65];
    const float* src = src0 + (long)blockIdx.z * src_zstr;
    u16* dst = dst0 + (long)blockIdx.z * dst_zstr;
    int r0 = blockIdx.y * 64, c0 = blockIdx.x * 64;
    int tx = threadIdx.x & 63, ty = threadIdx.x >> 6;  // 64 x 4
#pragma unroll
    for (int k = 0; k < 16; ++k)
        tile[ty + 4 * k][tx] = src[(long)(r0 + ty + 4 * k) * src_ld + c0 + tx];
    __syncthreads();
#pragma unroll
    for (int k = 0; k < 16; ++k)
        dst[(long)(c0 + ty + 4 * k) * dst_ld + r0 + tx] = f2bf(tile[tx][ty + 4 * k]);
}

__global__ __launch_bounds__(256) void cvt_x_k(const float* __restrict__ x,
                                               u16* __restrict__ xb)
{
    long i = ((long)blockIdx.x * 256 + threadIdx.x) * 4;
    float4 v = *(const float4*)(x + i);
    union { u16 s[4]; uint2 v2; } o;
    o.s[0] = f2bf(v.x); o.s[1] = f2bf(v.y); o.s[2] = f2bf(v.z); o.s[3] = f2bf(v.w);
    *(uint2*)(xb + i) = o.v2;
}

extern "C" void kernel_launch(void* const* d_in, const int* in_sizes, int n_in,
                              void* d_out, int out_size, void* d_ws, size_t ws_size,
                              hipStream_t stream) {
    (void)in_sizes; (void)n_in; (void)out_size; (void)ws_size;
    const int Hd = 2048, E = 8, I = 768, SH = 5632, T = 4096, CAP = 2048;

    const float* x    = (const float*)d_in[0];
    const float* rw   = (const float*)d_in[1];
    const float* egu  = (const float*)d_in[2];
    const float* edw  = (const float*)d_in[3];
    const float* sgw  = (const float*)d_in[4];
    const float* suw  = (const float*)d_in[5];
    const float* sdw  = (const float*)d_in[6];
    const float* segw = (const float*)d_in[7];
    float* out = (float*)d_out;
    float* logits = out + (size_t)T * Hd;

    char* wsp = (char*)d_ws;
    size_t off = 0;
    auto alloc = [&](size_t bytes) {
        void* p = wsp + off; off += (bytes + 255) & ~(size_t)255; return p;
    };
    u16* xb   = (u16*)alloc((size_t)T * Hd * 2);
    u16* Bgs  = (u16*)alloc((size_t)SH * Hd * 2);
    u16* Bus  = (u16*)alloc((size_t)SH * Hd * 2);
    u16* Bds  = (u16*)alloc((size_t)Hd * SH * 2);
    u16* Beg  = (u16*)alloc((size_t)E * I * Hd * 2);
    u16* Beu  = (u16*)alloc((size_t)E * I * Hd * 2);
    u16* Bed  = (u16*)alloc((size_t)E * Hd * I * 2);
    u16* hs   = (u16*)alloc((size_t)T * SH * 2);
    u16* eact = (u16*)alloc((size_t)E * CAP * I * 2);
    int2*   te   = (int2*)alloc((size_t)T * 8);
    float2* tw   = (float2*)alloc((size_t)T * 8);
    int*    tok  = (int*)alloc((size_t)E * CAP * 4);
    float*  wrow = (float*)alloc((size_t)E * CAP * 4);
    int*    cntp = (int*)alloc(64);
    float*  sig  = (float*)alloc((size_t)T * 4);

    hipFuncSetAttribute((const void*)gemm8_swiglu_k,
                        hipFuncAttributeMaxDynamicSharedMemorySize, 131072);
    hipFuncSetAttribute((const void*)gemm8e_swiglu_k,
                        hipFuncAttributeMaxDynamicSharedMemorySize, 131072);

    cvt_x_k<<<(T * Hd) / 1024, 256, 0, stream>>>(x, xb);
    router_k<<<T / 4, 256, 0, stream>>>(x, rw, segw, logits, te, tw, sig, T, Hd);
    compact_k<<<E, 256, 0, stream>>>(te, tw, tok, wrow, cntp, T, CAP);

    // weights f32 [K,N] -> bf16 [N,K], 64x64 tiles
    transpose_k<<<dim3(SH / 64, Hd / 64), 256, 0, stream>>>(sgw, 0, SH, Bgs, 0, Hd);
    transpose_k<<<dim3(SH / 64, Hd / 64), 256, 0, stream>>>(suw, 0, SH, Bus, 0, Hd);
    transpose_k<<<dim3(Hd / 64, SH / 64), 256, 0, stream>>>(sdw, 0, Hd, Bds, 0, SH);
    transpose_k<<<dim3(I / 64, Hd / 64, E), 256, 0, stream>>>(
        egu, (long)Hd * 2 * I, 2 * I, Beg, (long)I * Hd, Hd);
    transpose_k<<<dim3(I / 64, Hd / 64, E), 256, 0, stream>>>(
        egu + I, (long)Hd * 2 * I, 2 * I, Beu, (long)I * Hd, Hd);
    transpose_k<<<dim3(Hd / 64, I / 64, E), 256, 0, stream>>>(
        edw, (long)I * Hd, Hd, Bed, (long)Hd * I, I);

    // shared SwiGLU (8-phase, proven): hs[T,SH]; grid 704 (%8==0)
    gemm8_swiglu_k<<<dim3((SH / 128) * (T / 256)), 512, 131072, stream>>>(
        xb, Bgs, Bus, hs, Hd, SH / 128, SH);
    // shared down (2-phase, proven): out = sig * hs @ Bds^T
    gemm_down_k<<<dim3(Hd / 128, T / 128), 256, 0, stream>>>(
        hs, Bds, out, sig, SH, Hd);
    // expert SwiGLU (8-phase, token-gathered): eact[E*CAP, I]
    gemm8e_swiglu_k<<<dim3(I / 128, CAP / 256, E), 512, 131072, stream>>>(
        xb, Beg, Beu, tok, cntp, eact, Hd, I, CAP);
    // expert down (2-phase) + weighted scatter-add into out (K = I per expert)
    gemm_down_moe_k<<<dim3(Hd / 128, CAP / 128, E), 256, 0, stream>>>(
        eact, Bed, out, tok, wrow, cntp, I, Hd, CAP);
}